// Round 1
// baseline (384.465 us; speedup 1.0000x reference)
//
#include <hip/hip_runtime.h>
#include <float.h>

// Co_Attention collapsed:
//   S[b,n,m] = u_fea[b,n]·E·i_fea[b,m] + u_fea[b,n]·a + g·i_fea[b,m] + s0
//   E = Wu^T M Wi, a = Wu^T M bi, g = bu^T M Wi, s0 = bu^T M bi
// p_u = softmax_n(max_m S), p_i = softmax_m(max_n S)
// ws float layout: E[0..4095], a[4096..4159], g[4160..4223], s0[4224]

#define NBATCH 256
#define NSEQ   512   // Nu == Ni
#define DIM    64

__global__ __launch_bounds__(256) void coatt_prep(
    const float* __restrict__ M, const float* __restrict__ Wu,
    const float* __restrict__ bu, const float* __restrict__ Wi,
    const float* __restrict__ bi, float* __restrict__ ws)
{
    __shared__ float Al[64*64];   // holds M, then reused for Wu
    __shared__ float Wil[64*64];
    __shared__ float Tl[64*64];   // T = M @ Wi
    __shared__ float tb[64];      // tb = M @ bi
    const int t = threadIdx.x;
    for (int i = t; i < 4096; i += 256) { Al[i] = M[i]; Wil[i] = Wi[i]; }
    __syncthreads();
    for (int i = t; i < 4096; i += 256) {
        const int d = i >> 6, f = i & 63;
        float s = 0.f;
        #pragma unroll 8
        for (int e = 0; e < 64; ++e) s = fmaf(Al[d*64+e], Wil[e*64+f], s);
        Tl[i] = s;
    }
    if (t < 64) {
        float s = 0.f;
        #pragma unroll 8
        for (int e = 0; e < 64; ++e) s = fmaf(Al[t*64+e], bi[e], s);
        tb[t] = s;
    }
    __syncthreads();
    for (int i = t; i < 4096; i += 256) Al[i] = Wu[i];   // Al := Wu
    __syncthreads();
    for (int i = t; i < 4096; i += 256) {
        const int c = i >> 6, f = i & 63;
        float s = 0.f;
        #pragma unroll 8
        for (int d = 0; d < 64; ++d) s = fmaf(Al[d*64+c], Tl[d*64+f], s);
        ws[i] = s;                 // E[c,f]
    }
    if (t < 64) {
        float sa = 0.f, sg = 0.f;
        #pragma unroll 8
        for (int d = 0; d < 64; ++d) {
            sa = fmaf(Al[d*64+t], tb[d], sa);   // a[c] = sum_d Wu[d,c] tb[d]
            sg = fmaf(bu[d], Tl[d*64+t], sg);   // g[f] = sum_d bu[d] T[d,f]
        }
        ws[4096+t] = sa;
        ws[4160+t] = sg;
    }
    if (t == 0) {
        float s = 0.f;
        for (int d = 0; d < 64; ++d) s = fmaf(bu[d], tb[d], s);
        ws[4224] = s;
    }
}

// One block per batch. 256 threads as 16x16, each computing a 4x4 tile of S.
#define RSTRIDE 68   // 64 + 4 pad (keeps 16B alignment: 68*4 = 272 B)

__global__ __launch_bounds__(256) void coatt_main(
    const float* __restrict__ u_fea, const float* __restrict__ i_fea,
    const float* __restrict__ ws, float* __restrict__ out)
{
    __shared__ float El[64*64];          // E, row-major [c][f]
    __shared__ float Xl[64*RSTRIDE];     // X tile (n-rows x d)
    __shared__ float Yl[64*RSTRIDE];     // Y tile (m-rows x d); also U tile
    __shared__ float rt[64];             // r[n] for current n-tile
    __shared__ float gl[64];
    __shared__ float al[64];
    __shared__ float colmax[NSEQ];       // i_score accumulator
    __shared__ float uscore[NSEQ];       // u_score
    __shared__ float colpart[16*64];     // per-ty col-max partials
    __shared__ float red[16];
    __shared__ float s0s;

    const int b  = blockIdx.x;
    const int t  = threadIdx.x;
    const int ty = t >> 4, tx = t & 15;

    for (int i = t; i < 4096; i += 256) El[i] = ws[i];
    if (t < 64) { al[t] = ws[4096+t]; gl[t] = ws[4160+t]; }
    if (t == 0) s0s = ws[4224];
    for (int i = t; i < NSEQ; i += 256) colmax[i] = -FLT_MAX;
    __syncthreads();

    const float* ub = u_fea + (size_t)b * NSEQ * DIM;
    const float* ib = i_fea + (size_t)b * NSEQ * DIM;

    for (int nt = 0; nt < 8; ++nt) {
        // ---- load U tile (64x64) into Yl (aliased) ----
        #pragma unroll
        for (int q = 0; q < 4; ++q) {
            const int lin = t + q*256;          // float4 unit id, 0..1023
            const int row = lin >> 4, c4 = lin & 15;
            const float4 v = ((const float4*)(ub + (size_t)(nt*64 + row)*DIM))[c4];
            *((float4*)(Yl + row*RSTRIDE + c4*4)) = v;
        }
        __syncthreads();
        // ---- r[n] = U·a + s0 ----
        if (t < 64) {
            float s = s0s;
            #pragma unroll 8
            for (int c = 0; c < 64; ++c) s = fmaf(Yl[t*RSTRIDE+c], al[c], s);
            rt[t] = s;
        }
        // ---- X tile = U @ E + g ----
        {
            float4 xacc[4];
            #pragma unroll
            for (int j = 0; j < 4; ++j) xacc[j] = make_float4(0.f,0.f,0.f,0.f);
            for (int c = 0; c < 64; ++c) {
                const float4 e4 = ((const float4*)El)[c*16 + tx];
                #pragma unroll
                for (int j = 0; j < 4; ++j) {
                    const float u = Yl[(ty*4+j)*RSTRIDE + c];
                    xacc[j].x = fmaf(u, e4.x, xacc[j].x);
                    xacc[j].y = fmaf(u, e4.y, xacc[j].y);
                    xacc[j].z = fmaf(u, e4.z, xacc[j].z);
                    xacc[j].w = fmaf(u, e4.w, xacc[j].w);
                }
            }
            const float4 g4 = ((const float4*)gl)[tx];
            #pragma unroll
            for (int j = 0; j < 4; ++j) {
                xacc[j].x += g4.x; xacc[j].y += g4.y;
                xacc[j].z += g4.z; xacc[j].w += g4.w;
                *((float4*)(Xl + (ty*4+j)*RSTRIDE + tx*4)) = xacc[j];
            }
        }
        __syncthreads();

        float rj[4], rmax[4];
        #pragma unroll
        for (int j = 0; j < 4; ++j) { rj[j] = rt[ty*4+j]; rmax[j] = -FLT_MAX; }

        for (int mt = 0; mt < 8; ++mt) {
            // ---- load Y tile ----
            #pragma unroll
            for (int q = 0; q < 4; ++q) {
                const int lin = t + q*256;
                const int row = lin >> 4, c4 = lin & 15;
                const float4 v = ((const float4*)(ib + (size_t)(mt*64 + row)*DIM))[c4];
                *((float4*)(Yl + row*RSTRIDE + c4*4)) = v;
            }
            __syncthreads();
            // ---- 4x4 tile of S ----
            float acc[4][4];
            #pragma unroll
            for (int j = 0; j < 4; ++j)
                #pragma unroll
                for (int k = 0; k < 4; ++k) acc[j][k] = 0.f;
            #pragma unroll 4
            for (int d4 = 0; d4 < 16; ++d4) {
                float4 x4[4], y4[4];
                #pragma unroll
                for (int j = 0; j < 4; ++j)
                    x4[j] = *((const float4*)(Xl + (ty*4+j)*RSTRIDE + d4*4));
                #pragma unroll
                for (int k = 0; k < 4; ++k)
                    y4[k] = *((const float4*)(Yl + (tx*4+k)*RSTRIDE + d4*4));
                #pragma unroll
                for (int j = 0; j < 4; ++j)
                    #pragma unroll
                    for (int k = 0; k < 4; ++k) {
                        acc[j][k] = fmaf(x4[j].x, y4[k].x, acc[j][k]);
                        acc[j][k] = fmaf(x4[j].y, y4[k].y, acc[j][k]);
                        acc[j][k] = fmaf(x4[j].z, y4[k].z, acc[j][k]);
                        acc[j][k] = fmaf(x4[j].w, y4[k].w, acc[j][k]);
                    }
            }
            // ---- add r, update row/col maxes ----
            #pragma unroll
            for (int k = 0; k < 4; ++k) {
                float cm = -FLT_MAX;
                #pragma unroll
                for (int j = 0; j < 4; ++j) {
                    const float s = acc[j][k] + rj[j];
                    rmax[j] = fmaxf(rmax[j], s);
                    cm = fmaxf(cm, s);
                }
                colpart[ty*64 + tx*4 + k] = cm;
            }
            __syncthreads();
            if (t < 64) {
                float v = colpart[t];
                #pragma unroll
                for (int q = 1; q < 16; ++q) v = fmaxf(v, colpart[q*64 + t]);
                colmax[mt*64 + t] = fmaxf(colmax[mt*64 + t], v);
            }
            __syncthreads();
        }
        // ---- row-max reduce across tx (16 contiguous lanes in-wave) ----
        #pragma unroll
        for (int j = 0; j < 4; ++j) {
            float v = rmax[j];
            #pragma unroll
            for (int off = 1; off < 16; off <<= 1) v = fmaxf(v, __shfl_xor(v, off, 64));
            if (tx == 0) uscore[nt*64 + ty*4 + j] = v;
        }
        __syncthreads();
    }

    // ---- softmax over uscore -> p_u ----
    {
        const int lane = t & 63, wid = t >> 6;
        float v = fmaxf(uscore[t], uscore[t+256]);
        #pragma unroll
        for (int off = 1; off < 64; off <<= 1) v = fmaxf(v, __shfl_xor(v, off, 64));
        if (lane == 0) red[wid] = v;
        __syncthreads();
        const float m = fmaxf(fmaxf(red[0], red[1]), fmaxf(red[2], red[3]));
        const float e0 = __expf(uscore[t] - m);
        const float e1 = __expf(uscore[t+256] - m);
        float s = e0 + e1;
        #pragma unroll
        for (int off = 1; off < 64; off <<= 1) s += __shfl_xor(s, off, 64);
        if (lane == 0) red[4+wid] = s;
        __syncthreads();
        const float inv = 1.0f / (red[4]+red[5]+red[6]+red[7]);
        out[(size_t)b*NSEQ + t]       = e0 * inv;
        out[(size_t)b*NSEQ + t + 256] = e1 * inv;
    }
    __syncthreads();
    // ---- softmax over colmax -> p_i ----
    {
        const int lane = t & 63, wid = t >> 6;
        float v = fmaxf(colmax[t], colmax[t+256]);
        #pragma unroll
        for (int off = 1; off < 64; off <<= 1) v = fmaxf(v, __shfl_xor(v, off, 64));
        if (lane == 0) red[8+wid] = v;
        __syncthreads();
        const float m = fmaxf(fmaxf(red[8], red[9]), fmaxf(red[10], red[11]));
        const float e0 = __expf(colmax[t] - m);
        const float e1 = __expf(colmax[t+256] - m);
        float s = e0 + e1;
        #pragma unroll
        for (int off = 1; off < 64; off <<= 1) s += __shfl_xor(s, off, 64);
        if (lane == 0) red[12+wid] = s;
        __syncthreads();
        const float inv = 1.0f / (red[12]+red[13]+red[14]+red[15]);
        out[(size_t)NBATCH*NSEQ + (size_t)b*NSEQ + t]       = e0 * inv;
        out[(size_t)NBATCH*NSEQ + (size_t)b*NSEQ + t + 256] = e1 * inv;
    }
}

extern "C" void kernel_launch(void* const* d_in, const int* in_sizes, int n_in,
                              void* d_out, int out_size, void* d_ws, size_t ws_size,
                              hipStream_t stream) {
    const float* u_fea = (const float*)d_in[0];
    const float* i_fea = (const float*)d_in[1];
    const float* M     = (const float*)d_in[2];
    const float* Wu    = (const float*)d_in[3];
    const float* bu    = (const float*)d_in[4];
    const float* Wi    = (const float*)d_in[5];
    const float* bi    = (const float*)d_in[6];
    float* out = (float*)d_out;
    float* ws  = (float*)d_ws;

    coatt_prep<<<1, 256, 0, stream>>>(M, Wu, bu, Wi, bi, ws);
    coatt_main<<<NBATCH, 256, 0, stream>>>(u_fea, i_fea, ws, out);
}

// Round 2
// 171.960 us; speedup vs baseline: 2.2358x; 2.2358x over previous
//
#include <hip/hip_runtime.h>
#include <float.h>

// Co_Attention collapsed:
//   S[b,n,m] = u_fea[b,n]·E·i_fea[b,m] + u_fea[b,n]·a + g·i_fea[b,m] + s0
//   E = Wu^T M Wi, a = Wu^T M bi, g = bu^T M Wi, s0 = bu^T M bi
// p_u = softmax_n(max_m S), p_i = softmax_m(max_n S)
//
// Round 2: S and X=U@E on MFMA (v_mfma_f32_16x16x32_bf16) with 3-product
// split-bf16 (hi*hi + hi*lo + lo*hi); missing lo*lo term ~2^-18 relative.
// ws float layout: [4096..4159]=a, [4160..4223]=g, [4224]=s0,
//                  ushort frags at ws+4352: EhiT[4096], EloT[4096]

#define NBATCH 256
#define NSEQ   512
#define DIM    64

typedef __attribute__((ext_vector_type(8))) short short8;
typedef __attribute__((ext_vector_type(4))) float f32x4;

#define MFMA16(a,b,c) __builtin_amdgcn_mfma_f32_16x16x32_bf16(a,b,c,0,0,0)

__device__ __forceinline__ void cvt2(float f, unsigned short &h, unsigned short &l) {
    unsigned u = __float_as_uint(f);
    unsigned hb = (u + 0x7FFFu + ((u >> 16) & 1u)) >> 16;
    h = (unsigned short)hb;
    float r = f - __uint_as_float(hb << 16);
    unsigned u2 = __float_as_uint(r);
    l = (unsigned short)((u2 + 0x7FFFu + ((u2 >> 16) & 1u)) >> 16);
}

__device__ __forceinline__ void cvt8(const f32x4 a, const f32x4 b, short8 &hi, short8 &lo) {
    unsigned short h, l;
    #pragma unroll
    for (int i = 0; i < 4; ++i) { cvt2(a[i], h, l); hi[i] = (short)h; lo[i] = (short)l; }
    #pragma unroll
    for (int i = 0; i < 4; ++i) { cvt2(b[i], h, l); hi[4+i] = (short)h; lo[4+i] = (short)l; }
}

__global__ __launch_bounds__(256) void coatt_prep(
    const float* __restrict__ M, const float* __restrict__ Wu,
    const float* __restrict__ bu, const float* __restrict__ Wi,
    const float* __restrict__ bi, float* __restrict__ ws)
{
    __shared__ float Al[64*64];   // M, then Wu
    __shared__ float Wil[64*64];  // Wi, then E
    __shared__ float Tl[64*64];   // T = M @ Wi
    __shared__ float tb[64];      // tb = M @ bi
    const int t = threadIdx.x;
    for (int i = t; i < 4096; i += 256) { Al[i] = M[i]; Wil[i] = Wi[i]; }
    __syncthreads();
    for (int i = t; i < 4096; i += 256) {
        const int d = i >> 6, f = i & 63;
        float s = 0.f;
        #pragma unroll 8
        for (int e = 0; e < 64; ++e) s = fmaf(Al[d*64+e], Wil[e*64+f], s);
        Tl[i] = s;
    }
    if (t < 64) {
        float s = 0.f;
        #pragma unroll 8
        for (int e = 0; e < 64; ++e) s = fmaf(Al[t*64+e], bi[e], s);
        tb[t] = s;
    }
    __syncthreads();
    for (int i = t; i < 4096; i += 256) Al[i] = Wu[i];   // Al := Wu
    __syncthreads();
    // E[c,f] = sum_d Wu[d,c] T[d,f]  -> into Wil
    for (int i = t; i < 4096; i += 256) {
        const int c = i >> 6, f = i & 63;
        float s = 0.f;
        #pragma unroll 8
        for (int d = 0; d < 64; ++d) s = fmaf(Al[d*64+c], Tl[d*64+f], s);
        Wil[i] = s;
    }
    if (t < 64) {
        float sa = 0.f, sg = 0.f;
        #pragma unroll 8
        for (int d = 0; d < 64; ++d) {
            sa = fmaf(Al[d*64+t], tb[d], sa);   // a
            sg = fmaf(bu[d], Tl[d*64+t], sg);   // g
        }
        ws[4096+t] = sa;
        ws[4160+t] = sg;
    }
    if (t == 0) {
        float s = 0.f;
        for (int d = 0; d < 64; ++d) s = fmaf(bu[d], tb[d], s);
        ws[4224] = s;
    }
    __syncthreads();
    // frag-pack E^T as MFMA B-operand (hi/lo bf16):
    // frag (ft,ko): lane L=quad*16+f15 holds E[k=ko*32+quad*8+j][f=ft*16+f15]
    unsigned short* efh = (unsigned short*)(ws + 4352);
    unsigned short* efl = efh + 4096;
    for (int p = t; p < 4096; p += 256) {
        const int ft = p >> 10;
        const int q10 = p & 1023;
        const int ko = q10 >> 9;
        const int r9 = q10 & 511;
        const int L  = r9 >> 3, j = r9 & 7;
        const int quad = L >> 4, f15 = L & 15;
        const int k = ko*32 + quad*8 + j;
        const int f = ft*16 + f15;
        unsigned short h, l;
        cvt2(Wil[k*64 + f], h, l);
        efh[p] = h; efl[p] = l;
    }
}

// LDS layout (dynamic, bytes):
//  [0,65536)        YH  frag-packed bf16-hi of i_fea[b]
//  [65536,131072)   YL  frag-packed bf16-lo
//  [131072,148480)  Xs  per-wave staging 4 x (16x68 f32)
//  [148480,150528)  rl  r[n] (512 f32)
//  [150528,158720)  colp per-wave col-max 4 x 512 f32
//  [158720,160768)  uscore 512 f32
//  [160768,160832)  red 16 f32
#define LDS_BYTES 160832

__global__ __launch_bounds__(256) void coatt_main(
    const float* __restrict__ u_fea, const float* __restrict__ i_fea,
    const float* __restrict__ ws, float* __restrict__ out)
{
    extern __shared__ char sm[];
    unsigned short* YH = (unsigned short*)sm;
    unsigned short* YL = (unsigned short*)(sm + 65536);
    const int t    = threadIdx.x;
    const int lane = t & 63, w = t >> 6, quad = lane >> 4, l15 = lane & 15;
    float* Xs     = (float*)(sm + 131072) + w * (16*68);
    float* rl     = (float*)(sm + 148480);
    float* colp   = (float*)(sm + 150528);
    float* uscore = (float*)(sm + 158720);
    float* red    = (float*)(sm + 160768);

    const int b = blockIdx.x;
    const float* ub = u_fea + (size_t)b * NSEQ * DIM;
    const float* ib = i_fea + (size_t)b * NSEQ * DIM;

    // ---- E fragments (held in regs) ----
    const unsigned short* efh = (const unsigned short*)(ws + 4352);
    const unsigned short* efl = efh + 4096;
    short8 EH[4][2], EL[4][2];
    #pragma unroll
    for (int ft = 0; ft < 4; ++ft)
        #pragma unroll
        for (int ko = 0; ko < 2; ++ko) {
            EH[ft][ko] = *(const short8*)(efh + ((ft*2+ko)*64 + lane)*8);
            EL[ft][ko] = *(const short8*)(efl + ((ft*2+ko)*64 + lane)*8);
        }
    float gb[4];
    #pragma unroll
    for (int ft = 0; ft < 4; ++ft) gb[ft] = ws[4160 + ft*16 + l15];
    const float s0 = ws[4224];

    for (int i = t; i < 2048; i += 256) colp[i] = -FLT_MAX;

    // ---- Y -> frag-packed bf16 hi/lo in LDS ----
    #pragma unroll 4
    for (int it = 0; it < 16; ++it) {
        const int v = it*256 + t;            // 0..4095: (m, k-octet)
        const int m = v >> 3, kq = v & 7;
        const f32x4* gp = (const f32x4*)(ib + m*64 + kq*8);
        const f32x4 f0 = gp[0], f1 = gp[1];
        short8 sh, sl;
        cvt8(f0, f1, sh, sl);
        const int off = (m>>4)*1024 + (kq>>2)*512 + ((kq&3)*16 + (m&15))*8;
        *(short8*)(YH + off) = sh;
        *(short8*)(YL + off) = sl;
    }

    // ---- r[n] = U·a + s0 ----
    {
        const f32x4* av = (const f32x4*)(ws + 4096);
        for (int r = t; r < NSEQ; r += 256) {
            const f32x4* up = (const f32x4*)(ub + r*64);
            float s = s0;
            #pragma unroll
            for (int c4 = 0; c4 < 16; ++c4) {
                const f32x4 u4 = up[c4], a4 = av[c4];
                s = fmaf(u4[0],a4[0],s); s = fmaf(u4[1],a4[1],s);
                s = fmaf(u4[2],a4[2],s); s = fmaf(u4[3],a4[3],s);
            }
            rl[r] = s;
        }
    }
    __syncthreads();

    #pragma unroll
    for (int h = 0; h < 2; ++h) {
        const int base = h*256 + w*64;       // this wave's 64 rows
        short8 XH[4][2], XL[4][2];
        f32x4 rv[4];
        // ---- X-gen: 16-row groups via MFMA, keep as A-frags in regs ----
        #pragma unroll
        for (int g = 0; g < 4; ++g) {
            const float* up = ub + (size_t)(base + g*16 + l15)*64 + quad*8;
            const f32x4 u0 = *(const f32x4*)up;
            const f32x4 u1 = *(const f32x4*)(up+4);
            const f32x4 u2 = *(const f32x4*)(up+32);
            const f32x4 u3 = *(const f32x4*)(up+36);
            short8 UH0, UL0, UH1, UL1;
            cvt8(u0,u1,UH0,UL0); cvt8(u2,u3,UH1,UL1);
            #pragma unroll
            for (int ft = 0; ft < 4; ++ft) {
                f32x4 c = {0.f,0.f,0.f,0.f};
                c = MFMA16(UH0, EH[ft][0], c);
                c = MFMA16(UH1, EH[ft][1], c);
                c = MFMA16(UH0, EL[ft][0], c);
                c = MFMA16(UH1, EL[ft][1], c);
                c = MFMA16(UL0, EH[ft][0], c);
                c = MFMA16(UL1, EH[ft][1], c);
                #pragma unroll
                for (int rg = 0; rg < 4; ++rg)
                    Xs[(quad*4+rg)*68 + ft*16 + l15] = c[rg] + gb[ft];
            }
            // per-wave staging; DS pipe is in-order within a wave
            const float* xp = Xs + l15*68 + quad*8;
            const f32x4 x0 = *(const f32x4*)xp;
            const f32x4 x1 = *(const f32x4*)(xp+4);
            const f32x4 x2 = *(const f32x4*)(xp+32);
            const f32x4 x3 = *(const f32x4*)(xp+36);
            cvt8(x0,x1,XH[g][0],XL[g][0]);
            cvt8(x2,x3,XH[g][1],XL[g][1]);
            rv[g] = *(const f32x4*)(rl + base + g*16 + quad*4);
        }
        // ---- S m-loop ----
        f32x4 rm[4];
        #pragma unroll
        for (int g = 0; g < 4; ++g)
            rm[g] = (f32x4){-FLT_MAX,-FLT_MAX,-FLT_MAX,-FLT_MAX};
        for (int T = 0; T < 32; ++T) {
            const unsigned short* yh2 = YH + T*1024 + lane*8;
            const unsigned short* yl2 = YL + T*1024 + lane*8;
            const short8 BH0 = *(const short8*)(yh2);
            const short8 BH1 = *(const short8*)(yh2 + 512);
            const short8 BL0 = *(const short8*)(yl2);
            const short8 BL1 = *(const short8*)(yl2 + 512);
            float cm = -FLT_MAX;
            #pragma unroll
            for (int g = 0; g < 4; ++g) {
                f32x4 c = {0.f,0.f,0.f,0.f};
                c = MFMA16(XH[g][0], BH0, c);
                c = MFMA16(XH[g][1], BH1, c);
                c = MFMA16(XH[g][0], BL0, c);
                c = MFMA16(XH[g][1], BL1, c);
                c = MFMA16(XL[g][0], BH0, c);
                c = MFMA16(XL[g][1], BH1, c);
                #pragma unroll
                for (int rg = 0; rg < 4; ++rg) {
                    const float s = c[rg] + rv[g][rg];
                    rm[g][rg] = fmaxf(rm[g][rg], s);
                    cm = fmaxf(cm, s);
                }
            }
            cm = fmaxf(cm, __shfl_xor(cm, 16, 64));
            cm = fmaxf(cm, __shfl_xor(cm, 32, 64));
            if (lane < 16) {
                float* cp = colp + w*512 + T*16 + lane;
                *cp = fmaxf(*cp, cm);
            }
        }
        // ---- row-max write ----
        #pragma unroll
        for (int g = 0; g < 4; ++g)
            #pragma unroll
            for (int rg = 0; rg < 4; ++rg) {
                float v = rm[g][rg];
                v = fmaxf(v, __shfl_xor(v, 1, 64));
                v = fmaxf(v, __shfl_xor(v, 2, 64));
                v = fmaxf(v, __shfl_xor(v, 4, 64));
                v = fmaxf(v, __shfl_xor(v, 8, 64));
                if (l15 == 0) uscore[base + g*16 + quad*4 + rg] = v;
            }
    }
    __syncthreads();
    for (int c = t; c < NSEQ; c += 256) {
        const float v = fmaxf(fmaxf(colp[c], colp[512+c]),
                              fmaxf(colp[1024+c], colp[1536+c]));
        colp[c] = v;
    }
    __syncthreads();

    // ---- softmax(uscore) -> p_u ----
    {
        const int wid = t >> 6;
        float v = fmaxf(uscore[t], uscore[t+256]);
        #pragma unroll
        for (int off = 1; off < 64; off <<= 1) v = fmaxf(v, __shfl_xor(v, off, 64));
        if (lane == 0) red[wid] = v;
        __syncthreads();
        const float m = fmaxf(fmaxf(red[0], red[1]), fmaxf(red[2], red[3]));
        const float e0 = __expf(uscore[t] - m);
        const float e1 = __expf(uscore[t+256] - m);
        float s = e0 + e1;
        #pragma unroll
        for (int off = 1; off < 64; off <<= 1) s += __shfl_xor(s, off, 64);
        if (lane == 0) red[4+wid] = s;
        __syncthreads();
        const float inv = 1.0f / (red[4]+red[5]+red[6]+red[7]);
        out[(size_t)b*NSEQ + t]       = e0 * inv;
        out[(size_t)b*NSEQ + t + 256] = e1 * inv;
    }
    __syncthreads();
    // ---- softmax(colmax) -> p_i ----
    {
        const int wid = t >> 6;
        float v = fmaxf(colp[t], colp[t+256]);
        #pragma unroll
        for (int off = 1; off < 64; off <<= 1) v = fmaxf(v, __shfl_xor(v, off, 64));
        if (lane == 0) red[8+wid] = v;
        __syncthreads();
        const float m = fmaxf(fmaxf(red[8], red[9]), fmaxf(red[10], red[11]));
        const float e0 = __expf(colp[t] - m);
        const float e1 = __expf(colp[t+256] - m);
        float s = e0 + e1;
        #pragma unroll
        for (int off = 1; off < 64; off <<= 1) s += __shfl_xor(s, off, 64);
        if (lane == 0) red[12+wid] = s;
        __syncthreads();
        const float inv = 1.0f / (red[12]+red[13]+red[14]+red[15]);
        out[(size_t)NBATCH*NSEQ + (size_t)b*NSEQ + t]       = e0 * inv;
        out[(size_t)NBATCH*NSEQ + (size_t)b*NSEQ + t + 256] = e1 * inv;
    }
}

extern "C" void kernel_launch(void* const* d_in, const int* in_sizes, int n_in,
                              void* d_out, int out_size, void* d_ws, size_t ws_size,
                              hipStream_t stream) {
    const float* u_fea = (const float*)d_in[0];
    const float* i_fea = (const float*)d_in[1];
    const float* M     = (const float*)d_in[2];
    const float* Wu    = (const float*)d_in[3];
    const float* bu    = (const float*)d_in[4];
    const float* Wi    = (const float*)d_in[5];
    const float* bi    = (const float*)d_in[6];
    float* out = (float*)d_out;
    float* ws  = (float*)d_ws;

    coatt_prep<<<1, 256, 0, stream>>>(M, Wu, bu, Wi, bi, ws);
    coatt_main<<<NBATCH, 256, LDS_BYTES, stream>>>(u_fea, i_fea, ws, out);
}

// Round 3
// 153.114 us; speedup vs baseline: 2.5110x; 1.1231x over previous
//
#include <hip/hip_runtime.h>
#include <float.h>

// Co_Attention collapsed:
//   S[b,n,m] = u_fea[b,n]·E·i_fea[b,m] + u_fea[b,n]·a + g·i_fea[b,m] + s0
//   E = Wu^T M Wi, a = Wu^T M bi, g = bu^T M Wi, s0 = bu^T M bi
// p_u = softmax_n(max_m S), p_i = softmax_m(max_n S)
//
// Round 3: prep split into two tiny parallel kernels (64 blocks each) —
// the old single-block prep was ~100 us of serial LDS-scalar matmul.
// ws float layout: [4096..4159]=a, [4160..4223]=g, [4224]=s0,
//   ushort frags at ws+4352: EhiT[4096], EloT[4096]  (= ws floats [4352,8448))
//   scratch: T at [8448,12544), tb at [12544,12608)

#define NBATCH 256
#define NSEQ   512
#define DIM    64

typedef __attribute__((ext_vector_type(8))) short short8;
typedef __attribute__((ext_vector_type(4))) float f32x4;

#define MFMA16(a,b,c) __builtin_amdgcn_mfma_f32_16x16x32_bf16(a,b,c,0,0,0)

__device__ __forceinline__ void cvt2(float f, unsigned short &h, unsigned short &l) {
    unsigned u = __float_as_uint(f);
    unsigned hb = (u + 0x7FFFu + ((u >> 16) & 1u)) >> 16;
    h = (unsigned short)hb;
    float r = f - __uint_as_float(hb << 16);
    unsigned u2 = __float_as_uint(r);
    l = (unsigned short)((u2 + 0x7FFFu + ((u2 >> 16) & 1u)) >> 16);
}

__device__ __forceinline__ void cvt8(const f32x4 a, const f32x4 b, short8 &hi, short8 &lo) {
    unsigned short h, l;
    #pragma unroll
    for (int i = 0; i < 4; ++i) { cvt2(a[i], h, l); hi[i] = (short)h; lo[i] = (short)l; }
    #pragma unroll
    for (int i = 0; i < 4; ++i) { cvt2(b[i], h, l); hi[4+i] = (short)h; lo[4+i] = (short)l; }
}

// ---- prep1: block d computes T[d,:] = M[d,:]@Wi and tb[d] = M[d,:]·bi ----
__global__ __launch_bounds__(64) void coatt_prep1(
    const float* __restrict__ M, const float* __restrict__ Wi,
    const float* __restrict__ bi, float* __restrict__ ws)
{
    __shared__ float Ml[64];
    const int d = blockIdx.x, f = threadIdx.x;
    Ml[f] = M[d*64 + f];
    __syncthreads();
    float s = 0.f;
    #pragma unroll 8
    for (int e = 0; e < 64; ++e) s = fmaf(Ml[e], Wi[e*64 + f], s);
    ws[8448 + d*64 + f] = s;
    float p = Ml[f] * bi[f];
    #pragma unroll
    for (int off = 1; off < 64; off <<= 1) p += __shfl_xor(p, off, 64);
    if (f == 0) ws[12544 + d] = p;
}

// ---- prep2: block c computes E[c,:] (frag-packed hi/lo), a[c]; block 0 also g, s0 ----
__global__ __launch_bounds__(64) void coatt_prep2(
    const float* __restrict__ Wu, const float* __restrict__ bu,
    float* __restrict__ ws)
{
    __shared__ float col[64];
    const int c = blockIdx.x, f = threadIdx.x;
    const float* T = ws + 8448;
    col[f] = Wu[f*64 + c];          // Wu[d=f][c]
    __syncthreads();
    float s = 0.f;
    #pragma unroll 8
    for (int d = 0; d < 64; ++d) s = fmaf(col[d], T[d*64 + f], s);
    // frag-pack E[k=c][f] into B-operand layout
    unsigned short* efh = (unsigned short*)(ws + 4352);
    unsigned short* efl = efh + 4096;
    unsigned short h, l;
    cvt2(s, h, l);
    const int ko = c >> 5, quad = (c >> 3) & 3, j = c & 7;
    const int ft = f >> 4, f15 = f & 15;
    const int p = ft*1024 + ko*512 + (quad*16 + f15)*8 + j;
    efh[p] = h; efl[p] = l;
    // a[c] = sum_d Wu[d,c] * tb[d]
    float pa = col[f] * ws[12544 + f];
    #pragma unroll
    for (int off = 1; off < 64; off <<= 1) pa += __shfl_xor(pa, off, 64);
    if (f == 0) ws[4096 + c] = pa;
    if (c == 0) {
        // g[f] = sum_d bu[d] * T[d,f]
        float sg = 0.f;
        #pragma unroll 8
        for (int d = 0; d < 64; ++d) sg = fmaf(bu[d], T[d*64 + f], sg);
        ws[4160 + f] = sg;
        // s0 = dot(bu, tb)
        float ps = bu[f] * ws[12544 + f];
        #pragma unroll
        for (int off = 1; off < 64; off <<= 1) ps += __shfl_xor(ps, off, 64);
        if (f == 0) ws[4224] = ps;
    }
}

// LDS layout (dynamic, bytes):
//  [0,65536)        YH  frag-packed bf16-hi of i_fea[b]
//  [65536,131072)   YL  frag-packed bf16-lo
//  [131072,148480)  Xs  per-wave staging 4 x (16x68 f32)
//  [148480,150528)  rl  r[n] (512 f32)
//  [150528,158720)  colp per-wave col-max 4 x 512 f32
//  [158720,160768)  uscore 512 f32
//  [160768,160832)  red 16 f32
#define LDS_BYTES 160832

__global__ __launch_bounds__(256) void coatt_main(
    const float* __restrict__ u_fea, const float* __restrict__ i_fea,
    const float* __restrict__ ws, float* __restrict__ out)
{
    extern __shared__ char sm[];
    unsigned short* YH = (unsigned short*)sm;
    unsigned short* YL = (unsigned short*)(sm + 65536);
    const int t    = threadIdx.x;
    const int lane = t & 63, w = t >> 6, quad = lane >> 4, l15 = lane & 15;
    float* Xs     = (float*)(sm + 131072) + w * (16*68);
    float* rl     = (float*)(sm + 148480);
    float* colp   = (float*)(sm + 150528);
    float* uscore = (float*)(sm + 158720);
    float* red    = (float*)(sm + 160768);

    const int b = blockIdx.x;
    const float* ub = u_fea + (size_t)b * NSEQ * DIM;
    const float* ib = i_fea + (size_t)b * NSEQ * DIM;

    // ---- E fragments (held in regs) ----
    const unsigned short* efh = (const unsigned short*)(ws + 4352);
    const unsigned short* efl = efh + 4096;
    short8 EH[4][2], EL[4][2];
    #pragma unroll
    for (int ft = 0; ft < 4; ++ft)
        #pragma unroll
        for (int ko = 0; ko < 2; ++ko) {
            EH[ft][ko] = *(const short8*)(efh + ((ft*2+ko)*64 + lane)*8);
            EL[ft][ko] = *(const short8*)(efl + ((ft*2+ko)*64 + lane)*8);
        }
    float gb[4];
    #pragma unroll
    for (int ft = 0; ft < 4; ++ft) gb[ft] = ws[4160 + ft*16 + l15];
    const float s0 = ws[4224];

    for (int i = t; i < 2048; i += 256) colp[i] = -FLT_MAX;

    // ---- Y -> frag-packed bf16 hi/lo in LDS ----
    #pragma unroll 4
    for (int it = 0; it < 16; ++it) {
        const int v = it*256 + t;            // 0..4095: (m, k-octet)
        const int m = v >> 3, kq = v & 7;
        const f32x4* gp = (const f32x4*)(ib + m*64 + kq*8);
        const f32x4 f0 = gp[0], f1 = gp[1];
        short8 sh, sl;
        cvt8(f0, f1, sh, sl);
        const int off = (m>>4)*1024 + (kq>>2)*512 + ((kq&3)*16 + (m&15))*8;
        *(short8*)(YH + off) = sh;
        *(short8*)(YL + off) = sl;
    }

    // ---- r[n] = U·a + s0 ----
    {
        const f32x4* av = (const f32x4*)(ws + 4096);
        for (int r = t; r < NSEQ; r += 256) {
            const f32x4* up = (const f32x4*)(ub + r*64);
            float s = s0;
            #pragma unroll
            for (int c4 = 0; c4 < 16; ++c4) {
                const f32x4 u4 = up[c4], a4 = av[c4];
                s = fmaf(u4[0],a4[0],s); s = fmaf(u4[1],a4[1],s);
                s = fmaf(u4[2],a4[2],s); s = fmaf(u4[3],a4[3],s);
            }
            rl[r] = s;
        }
    }
    __syncthreads();

    #pragma unroll
    for (int h = 0; h < 2; ++h) {
        const int base = h*256 + w*64;       // this wave's 64 rows
        short8 XH[4][2], XL[4][2];
        f32x4 rv[4];
        // ---- X-gen: 16-row groups via MFMA, keep as A-frags in regs ----
        #pragma unroll
        for (int g = 0; g < 4; ++g) {
            const float* up = ub + (size_t)(base + g*16 + l15)*64 + quad*8;
            const f32x4 u0 = *(const f32x4*)up;
            const f32x4 u1 = *(const f32x4*)(up+4);
            const f32x4 u2 = *(const f32x4*)(up+32);
            const f32x4 u3 = *(const f32x4*)(up+36);
            short8 UH0, UL0, UH1, UL1;
            cvt8(u0,u1,UH0,UL0); cvt8(u2,u3,UH1,UL1);
            #pragma unroll
            for (int ft = 0; ft < 4; ++ft) {
                f32x4 c = {0.f,0.f,0.f,0.f};
                c = MFMA16(UH0, EH[ft][0], c);
                c = MFMA16(UH1, EH[ft][1], c);
                c = MFMA16(UH0, EL[ft][0], c);
                c = MFMA16(UH1, EL[ft][1], c);
                c = MFMA16(UL0, EH[ft][0], c);
                c = MFMA16(UL1, EH[ft][1], c);
                #pragma unroll
                for (int rg = 0; rg < 4; ++rg)
                    Xs[(quad*4+rg)*68 + ft*16 + l15] = c[rg] + gb[ft];
            }
            // per-wave staging; DS pipe is in-order within a wave
            const float* xp = Xs + l15*68 + quad*8;
            const f32x4 x0 = *(const f32x4*)xp;
            const f32x4 x1 = *(const f32x4*)(xp+4);
            const f32x4 x2 = *(const f32x4*)(xp+32);
            const f32x4 x3 = *(const f32x4*)(xp+36);
            cvt8(x0,x1,XH[g][0],XL[g][0]);
            cvt8(x2,x3,XH[g][1],XL[g][1]);
            rv[g] = *(const f32x4*)(rl + base + g*16 + quad*4);
        }
        // ---- S m-loop ----
        f32x4 rm[4];
        #pragma unroll
        for (int g = 0; g < 4; ++g)
            rm[g] = (f32x4){-FLT_MAX,-FLT_MAX,-FLT_MAX,-FLT_MAX};
        for (int T = 0; T < 32; ++T) {
            const unsigned short* yh2 = YH + T*1024 + lane*8;
            const unsigned short* yl2 = YL + T*1024 + lane*8;
            const short8 BH0 = *(const short8*)(yh2);
            const short8 BH1 = *(const short8*)(yh2 + 512);
            const short8 BL0 = *(const short8*)(yl2);
            const short8 BL1 = *(const short8*)(yl2 + 512);
            float cm = -FLT_MAX;
            #pragma unroll
            for (int g = 0; g < 4; ++g) {
                f32x4 c = {0.f,0.f,0.f,0.f};
                c = MFMA16(XH[g][0], BH0, c);
                c = MFMA16(XH[g][1], BH1, c);
                c = MFMA16(XH[g][0], BL0, c);
                c = MFMA16(XH[g][1], BL1, c);
                c = MFMA16(XL[g][0], BH0, c);
                c = MFMA16(XL[g][1], BH1, c);
                #pragma unroll
                for (int rg = 0; rg < 4; ++rg) {
                    const float s = c[rg] + rv[g][rg];
                    rm[g][rg] = fmaxf(rm[g][rg], s);
                    cm = fmaxf(cm, s);
                }
            }
            cm = fmaxf(cm, __shfl_xor(cm, 16, 64));
            cm = fmaxf(cm, __shfl_xor(cm, 32, 64));
            if (lane < 16) {
                float* cp = colp + w*512 + T*16 + lane;
                *cp = fmaxf(*cp, cm);
            }
        }
        // ---- row-max write ----
        #pragma unroll
        for (int g = 0; g < 4; ++g)
            #pragma unroll
            for (int rg = 0; rg < 4; ++rg) {
                float v = rm[g][rg];
                v = fmaxf(v, __shfl_xor(v, 1, 64));
                v = fmaxf(v, __shfl_xor(v, 2, 64));
                v = fmaxf(v, __shfl_xor(v, 4, 64));
                v = fmaxf(v, __shfl_xor(v, 8, 64));
                if (l15 == 0) uscore[base + g*16 + quad*4 + rg] = v;
            }
    }
    __syncthreads();
    for (int c = t; c < NSEQ; c += 256) {
        const float v = fmaxf(fmaxf(colp[c], colp[512+c]),
                              fmaxf(colp[1024+c], colp[1536+c]));
        colp[c] = v;
    }
    __syncthreads();

    // ---- softmax(uscore) -> p_u ----
    {
        const int wid = t >> 6;
        float v = fmaxf(uscore[t], uscore[t+256]);
        #pragma unroll
        for (int off = 1; off < 64; off <<= 1) v = fmaxf(v, __shfl_xor(v, off, 64));
        if (lane == 0) red[wid] = v;
        __syncthreads();
        const float m = fmaxf(fmaxf(red[0], red[1]), fmaxf(red[2], red[3]));
        const float e0 = __expf(uscore[t] - m);
        const float e1 = __expf(uscore[t+256] - m);
        float s = e0 + e1;
        #pragma unroll
        for (int off = 1; off < 64; off <<= 1) s += __shfl_xor(s, off, 64);
        if (lane == 0) red[4+wid] = s;
        __syncthreads();
        const float inv = 1.0f / (red[4]+red[5]+red[6]+red[7]);
        out[(size_t)b*NSEQ + t]       = e0 * inv;
        out[(size_t)b*NSEQ + t + 256] = e1 * inv;
    }
    __syncthreads();
    // ---- softmax(colmax) -> p_i ----
    {
        const int wid = t >> 6;
        float v = fmaxf(colp[t], colp[t+256]);
        #pragma unroll
        for (int off = 1; off < 64; off <<= 1) v = fmaxf(v, __shfl_xor(v, off, 64));
        if (lane == 0) red[8+wid] = v;
        __syncthreads();
        const float m = fmaxf(fmaxf(red[8], red[9]), fmaxf(red[10], red[11]));
        const float e0 = __expf(colp[t] - m);
        const float e1 = __expf(colp[t+256] - m);
        float s = e0 + e1;
        #pragma unroll
        for (int off = 1; off < 64; off <<= 1) s += __shfl_xor(s, off, 64);
        if (lane == 0) red[12+wid] = s;
        __syncthreads();
        const float inv = 1.0f / (red[12]+red[13]+red[14]+red[15]);
        out[(size_t)NBATCH*NSEQ + (size_t)b*NSEQ + t]       = e0 * inv;
        out[(size_t)NBATCH*NSEQ + (size_t)b*NSEQ + t + 256] = e1 * inv;
    }
}

extern "C" void kernel_launch(void* const* d_in, const int* in_sizes, int n_in,
                              void* d_out, int out_size, void* d_ws, size_t ws_size,
                              hipStream_t stream) {
    const float* u_fea = (const float*)d_in[0];
    const float* i_fea = (const float*)d_in[1];
    const float* M     = (const float*)d_in[2];
    const float* Wu    = (const float*)d_in[3];
    const float* bu    = (const float*)d_in[4];
    const float* Wi    = (const float*)d_in[5];
    const float* bi    = (const float*)d_in[6];
    float* out = (float*)d_out;
    float* ws  = (float*)d_ws;

    coatt_prep1<<<64, 64, 0, stream>>>(M, Wi, bi, ws);
    coatt_prep2<<<64, 64, 0, stream>>>(Wu, bu, ws);
    coatt_main<<<NBATCH, 256, LDS_BYTES, stream>>>(u_fea, i_fea, ws, out);
}

// Round 4
// 148.794 us; speedup vs baseline: 2.5839x; 1.0290x over previous
//
#include <hip/hip_runtime.h>
#include <float.h>

// Co_Attention collapsed:
//   S[b,n,m] = u_fea[b,n]·E·i_fea[b,m] + u_fea[b,n]·a + g·i_fea[b,m] + s0
//   E = Wu^T M Wi, a = Wu^T M bi, g = bu^T M Wi, s0 = bu^T M bi
// p_u = softmax_n(max_m S), p_i = softmax_m(max_n S)
//
// Round 4: 512-thread blocks (8 waves = 2/SIMD so MFMA of one wave overlaps
// VALU/LDS of the other), bias folded into MFMA C-init, colp/uscore aliased
// into dead Xs region to fit LDS.
// ws float layout: [4096..4159]=a, [4160..4223]=g, [4224]=s0,
//   ushort frags at ws+4352: EhiT[4096], EloT[4096]
//   scratch: T at [8448,12544), tb at [12544,12608)

#define NBATCH 256
#define NSEQ   512
#define DIM    64

typedef __attribute__((ext_vector_type(8))) short short8;
typedef __attribute__((ext_vector_type(4))) float f32x4;

#define MFMA16(a,b,c) __builtin_amdgcn_mfma_f32_16x16x32_bf16(a,b,c,0,0,0)

__device__ __forceinline__ void cvt2(float f, unsigned short &h, unsigned short &l) {
    unsigned u = __float_as_uint(f);
    unsigned hb = (u + 0x7FFFu + ((u >> 16) & 1u)) >> 16;
    h = (unsigned short)hb;
    float r = f - __uint_as_float(hb << 16);
    unsigned u2 = __float_as_uint(r);
    l = (unsigned short)((u2 + 0x7FFFu + ((u2 >> 16) & 1u)) >> 16);
}

__device__ __forceinline__ void cvt8(const f32x4 a, const f32x4 b, short8 &hi, short8 &lo) {
    unsigned short h, l;
    #pragma unroll
    for (int i = 0; i < 4; ++i) { cvt2(a[i], h, l); hi[i] = (short)h; lo[i] = (short)l; }
    #pragma unroll
    for (int i = 0; i < 4; ++i) { cvt2(b[i], h, l); hi[4+i] = (short)h; lo[4+i] = (short)l; }
}

// ---- prep1: block d computes T[d,:] = M[d,:]@Wi and tb[d] = M[d,:]·bi ----
__global__ __launch_bounds__(64) void coatt_prep1(
    const float* __restrict__ M, const float* __restrict__ Wi,
    const float* __restrict__ bi, float* __restrict__ ws)
{
    __shared__ float Ml[64];
    const int d = blockIdx.x, f = threadIdx.x;
    Ml[f] = M[d*64 + f];
    __syncthreads();
    float s = 0.f;
    #pragma unroll 8
    for (int e = 0; e < 64; ++e) s = fmaf(Ml[e], Wi[e*64 + f], s);
    ws[8448 + d*64 + f] = s;
    float p = Ml[f] * bi[f];
    #pragma unroll
    for (int off = 1; off < 64; off <<= 1) p += __shfl_xor(p, off, 64);
    if (f == 0) ws[12544 + d] = p;
}

// ---- prep2: block c computes E[c,:] (frag-packed hi/lo), a[c]; block 0 also g, s0 ----
__global__ __launch_bounds__(64) void coatt_prep2(
    const float* __restrict__ Wu, const float* __restrict__ bu,
    float* __restrict__ ws)
{
    __shared__ float col[64];
    const int c = blockIdx.x, f = threadIdx.x;
    const float* T = ws + 8448;
    col[f] = Wu[f*64 + c];          // Wu[d=f][c]
    __syncthreads();
    float s = 0.f;
    #pragma unroll 8
    for (int d = 0; d < 64; ++d) s = fmaf(col[d], T[d*64 + f], s);
    unsigned short* efh = (unsigned short*)(ws + 4352);
    unsigned short* efl = efh + 4096;
    unsigned short h, l;
    cvt2(s, h, l);
    const int ko = c >> 5, quad = (c >> 3) & 3, j = c & 7;
    const int ft = f >> 4, f15 = f & 15;
    const int p = ft*1024 + ko*512 + (quad*16 + f15)*8 + j;
    efh[p] = h; efl[p] = l;
    float pa = col[f] * ws[12544 + f];
    #pragma unroll
    for (int off = 1; off < 64; off <<= 1) pa += __shfl_xor(pa, off, 64);
    if (f == 0) ws[4096 + c] = pa;
    if (c == 0) {
        float sg = 0.f;
        #pragma unroll 8
        for (int d = 0; d < 64; ++d) sg = fmaf(bu[d], T[d*64 + f], sg);
        ws[4160 + f] = sg;
        float ps = bu[f] * ws[12544 + f];
        #pragma unroll
        for (int off = 1; off < 64; off <<= 1) ps += __shfl_xor(ps, off, 64);
        if (f == 0) ws[4224] = ps;
    }
}

// LDS layout (dynamic, bytes):
//  [0,65536)         YH  frag-packed bf16-hi of i_fea[b] (512 rows)
//  [65536,131072)    YL  frag-packed bf16-lo
//  [131072,149504)   Xs  per-wave staging 8 x (16x36 f32)   [X-gen phase]
//     after X-gen barrier, same region:
//     [131072,147456) colp 8 x 512 f32;  [147456,149504) uscore 512 f32
//  [149504,151552)   rl  r[n] 512 f32    [X-gen phase]; red 16 f32 after
#define LDS_BYTES 151552

__global__ __launch_bounds__(512, 2) void coatt_main(
    const float* __restrict__ u_fea, const float* __restrict__ i_fea,
    const float* __restrict__ ws, float* __restrict__ out)
{
    extern __shared__ char sm[];
    unsigned short* YH = (unsigned short*)sm;
    unsigned short* YL = (unsigned short*)(sm + 65536);
    const int t    = threadIdx.x;
    const int lane = t & 63, w = t >> 6, quad = lane >> 4, l15 = lane & 15;
    float* Xsw    = (float*)(sm + 131072) + w * 576;   // 16 x 36
    float* rl     = (float*)(sm + 149504);
    float* colp   = (float*)(sm + 131072);             // after X-gen
    float* uscore = (float*)(sm + 147456);             // after X-gen
    float* red    = (float*)(sm + 149504);             // aliases rl (dead)

    const int b = blockIdx.x;
    const float* ub = u_fea + (size_t)b * NSEQ * DIM;
    const float* ib = i_fea + (size_t)b * NSEQ * DIM;

    // ---- E fragments (regs) ----
    const unsigned short* efh = (const unsigned short*)(ws + 4352);
    const unsigned short* efl = efh + 4096;
    short8 EH[4][2], EL[4][2];
    #pragma unroll
    for (int ft = 0; ft < 4; ++ft)
        #pragma unroll
        for (int ko = 0; ko < 2; ++ko) {
            EH[ft][ko] = *(const short8*)(efh + ((ft*2+ko)*64 + lane)*8);
            EL[ft][ko] = *(const short8*)(efl + ((ft*2+ko)*64 + lane)*8);
        }
    float gb[4];
    #pragma unroll
    for (int ft = 0; ft < 4; ++ft) gb[ft] = ws[4160 + ft*16 + l15];
    const float s0 = ws[4224];

    // ---- Y -> frag-packed bf16 hi/lo in LDS (all 512 rows) ----
    #pragma unroll
    for (int it = 0; it < 8; ++it) {
        const int v = it*512 + t;            // (m, k-octet)
        const int m = v >> 3, kq = v & 7;
        const f32x4* gp = (const f32x4*)(ib + m*64 + kq*8);
        const f32x4 f0 = gp[0], f1 = gp[1];
        short8 sh, sl;
        cvt8(f0, f1, sh, sl);
        const int off = (m>>4)*1024 + (kq>>2)*512 + ((kq&3)*16 + (m&15))*8;
        *(short8*)(YH + off) = sh;
        *(short8*)(YL + off) = sl;
    }

    // ---- r[n] = U·a + s0 (one row per thread) ----
    {
        const f32x4* av = (const f32x4*)(ws + 4096);
        const f32x4* up = (const f32x4*)(ub + t*64);
        float s = s0;
        #pragma unroll
        for (int c4 = 0; c4 < 16; ++c4) {
            const f32x4 u4 = up[c4], a4 = av[c4];
            s = fmaf(u4[0],a4[0],s); s = fmaf(u4[1],a4[1],s);
            s = fmaf(u4[2],a4[2],s); s = fmaf(u4[3],a4[3],s);
        }
        rl[t] = s;
    }
    __syncthreads();

    // ---- X-gen: wave w owns rows [w*64, w*64+64), A-frags stay in regs ----
    const int base = w*64;
    short8 XH[4][2], XL[4][2];
    f32x4 rv[4];
    #pragma unroll
    for (int g = 0; g < 4; ++g) {
        const float* up = ub + (size_t)(base + g*16 + l15)*64 + quad*8;
        const f32x4 u0 = *(const f32x4*)up;
        const f32x4 u1 = *(const f32x4*)(up+4);
        const f32x4 u2 = *(const f32x4*)(up+32);
        const f32x4 u3 = *(const f32x4*)(up+36);
        short8 UH0, UL0, UH1, UL1;
        cvt8(u0,u1,UH0,UL0); cvt8(u2,u3,UH1,UL1);
        #pragma unroll
        for (int fp = 0; fp < 2; ++fp) {       // f-half: cols [fp*32, fp*32+32)
            #pragma unroll
            for (int fh = 0; fh < 2; ++fh) {
                const int ft = fp*2 + fh;
                f32x4 c = {gb[ft], gb[ft], gb[ft], gb[ft]};   // +g folded in
                c = MFMA16(UH0, EH[ft][0], c);
                c = MFMA16(UH1, EH[ft][1], c);
                c = MFMA16(UH0, EL[ft][0], c);
                c = MFMA16(UH1, EL[ft][1], c);
                c = MFMA16(UL0, EH[ft][0], c);
                c = MFMA16(UL1, EH[ft][1], c);
                #pragma unroll
                for (int rg = 0; rg < 4; ++rg)
                    Xsw[(quad*4+rg)*36 + fh*16 + l15] = c[rg];
            }
            // transpose read (wave-local; DS pipe is in-order per wave)
            const float* xp = Xsw + l15*36 + quad*8;
            f32x4 x0, x1;
            {   // stride 36 is 8B-aligned only: use float2 loads
                float2 p0 = *(const float2*)(xp);
                float2 p1 = *(const float2*)(xp+2);
                float2 p2 = *(const float2*)(xp+4);
                float2 p3 = *(const float2*)(xp+6);
                x0 = (f32x4){p0.x, p0.y, p1.x, p1.y};
                x1 = (f32x4){p2.x, p2.y, p3.x, p3.y};
            }
            cvt8(x0, x1, XH[g][fp], XL[g][fp]);
        }
        rv[g] = *(const f32x4*)(rl + base + g*16 + quad*4);
    }
    __syncthreads();            // Xs/rl dead; colp/uscore/red regions live now
    for (int i = t; i < 4096; i += 512) colp[i] = -FLT_MAX;
    __syncthreads();

    // ---- S-loop over all 32 m-tiles ----
    f32x4 rm[4];
    #pragma unroll
    for (int g = 0; g < 4; ++g)
        rm[g] = (f32x4){-FLT_MAX,-FLT_MAX,-FLT_MAX,-FLT_MAX};
    for (int T = 0; T < 32; ++T) {
        const unsigned short* yh2 = YH + T*1024 + lane*8;
        const unsigned short* yl2 = YL + T*1024 + lane*8;
        const short8 BH0 = *(const short8*)(yh2);
        const short8 BH1 = *(const short8*)(yh2 + 512);
        const short8 BL0 = *(const short8*)(yl2);
        const short8 BL1 = *(const short8*)(yl2 + 512);
        float cg[4];
        #pragma unroll
        for (int g = 0; g < 4; ++g) {
            f32x4 c = rv[g];                  // +r[n] folded into C-init
            c = MFMA16(XH[g][0], BH0, c);
            c = MFMA16(XH[g][1], BH1, c);
            c = MFMA16(XH[g][0], BL0, c);
            c = MFMA16(XH[g][1], BL1, c);
            c = MFMA16(XL[g][0], BH0, c);
            c = MFMA16(XL[g][1], BH1, c);
            rm[g][0] = fmaxf(rm[g][0], c[0]);
            rm[g][1] = fmaxf(rm[g][1], c[1]);
            rm[g][2] = fmaxf(rm[g][2], c[2]);
            rm[g][3] = fmaxf(rm[g][3], c[3]);
            cg[g] = fmaxf(fmaxf(c[0], c[1]), fmaxf(c[2], c[3]));
        }
        float cm = fmaxf(fmaxf(cg[0], cg[1]), fmaxf(cg[2], cg[3]));
        cm = fmaxf(cm, __shfl_xor(cm, 16, 64));
        cm = fmaxf(cm, __shfl_xor(cm, 32, 64));
        if (lane < 16) {
            float* cp = colp + w*512 + T*16 + lane;
            *cp = fmaxf(*cp, cm);
        }
    }
    // ---- row-max write ----
    #pragma unroll
    for (int g = 0; g < 4; ++g)
        #pragma unroll
        for (int rg = 0; rg < 4; ++rg) {
            float v = rm[g][rg];
            v = fmaxf(v, __shfl_xor(v, 1, 64));
            v = fmaxf(v, __shfl_xor(v, 2, 64));
            v = fmaxf(v, __shfl_xor(v, 4, 64));
            v = fmaxf(v, __shfl_xor(v, 8, 64));
            if (l15 == 0) uscore[base + g*16 + quad*4 + rg] = v;
        }
    __syncthreads();

    // ---- softmax(uscore) -> p_u ----
    {
        float v = uscore[t];
        float m = v;
        #pragma unroll
        for (int off = 1; off < 64; off <<= 1) m = fmaxf(m, __shfl_xor(m, off, 64));
        if (lane == 0) red[w] = m;
        __syncthreads();
        m = red[0];
        #pragma unroll
        for (int q = 1; q < 8; ++q) m = fmaxf(m, red[q]);
        const float e = __expf(v - m);
        float s = e;
        #pragma unroll
        for (int off = 1; off < 64; off <<= 1) s += __shfl_xor(s, off, 64);
        if (lane == 0) red[8+w] = s;
        __syncthreads();
        float sum = red[8];
        #pragma unroll
        for (int q = 1; q < 8; ++q) sum += red[8+q];
        out[(size_t)b*NSEQ + t] = e * (1.0f / sum);
    }
    __syncthreads();
    // ---- softmax(colmax 8-slice reduce) -> p_i ----
    {
        float v = colp[t];
        #pragma unroll
        for (int s8 = 1; s8 < 8; ++s8) v = fmaxf(v, colp[s8*512 + t]);
        float m = v;
        #pragma unroll
        for (int off = 1; off < 64; off <<= 1) m = fmaxf(m, __shfl_xor(m, off, 64));
        if (lane == 0) red[w] = m;
        __syncthreads();
        m = red[0];
        #pragma unroll
        for (int q = 1; q < 8; ++q) m = fmaxf(m, red[q]);
        const float e = __expf(v - m);
        float s = e;
        #pragma unroll
        for (int off = 1; off < 64; off <<= 1) s += __shfl_xor(s, off, 64);
        if (lane == 0) red[8+w] = s;
        __syncthreads();
        float sum = red[8];
        #pragma unroll
        for (int q = 1; q < 8; ++q) sum += red[8+q];
        out[(size_t)NBATCH*NSEQ + (size_t)b*NSEQ + t] = e * (1.0f / sum);
    }
}

extern "C" void kernel_launch(void* const* d_in, const int* in_sizes, int n_in,
                              void* d_out, int out_size, void* d_ws, size_t ws_size,
                              hipStream_t stream) {
    const float* u_fea = (const float*)d_in[0];
    const float* i_fea = (const float*)d_in[1];
    const float* M     = (const float*)d_in[2];
    const float* Wu    = (const float*)d_in[3];
    const float* bu    = (const float*)d_in[4];
    const float* Wi    = (const float*)d_in[5];
    const float* bi    = (const float*)d_in[6];
    float* out = (float*)d_out;
    float* ws  = (float*)d_ws;

    coatt_prep1<<<64, 64, 0, stream>>>(M, Wi, bi, ws);
    coatt_prep2<<<64, 64, 0, stream>>>(Wu, bu, ws);
    coatt_main<<<NBATCH, 512, LDS_BYTES, stream>>>(u_fea, i_fea, ws, out);
}

// Round 5
// 140.395 us; speedup vs baseline: 2.7385x; 1.0598x over previous
//
#include <hip/hip_runtime.h>
#include <hip/hip_bf16.h>
#include <float.h>

// Co_Attention collapsed:
//   S[b,n,m] = u_fea[b,n]·E·i_fea[b,m] + u_fea[b,n]·a + g·i_fea[b,m] + s0
//   E = Wu^T M Wi, a = Wu^T M bi, g = bu^T M Wi, s0 = bu^T M bi
// p_u = softmax_n(max_m S), p_i = softmax_m(max_n S)
//
// Round 5: transpose-free X via operand-swapped MFMA (X^T = E^T U^T) plus a
// fixed k-permutation tau baked into the Y-pack, so S-matmul A-frags are pure
// register renames of the X^T C-tiles. r[n] folded into X-gen (kills 32 MB of
// re-reads). colp RMW -> single store. Packed bf16 cvt.
// tau: slot(p,quad,j) <-> k = ((j>>2)*2+p)*16 + quad*4 + (j&3)
// ws float layout: [4096..4159]=a, [4160..4223]=g, [4224]=s0,
//   ushort frags at ws+4352: EhiT[4096], EloT[4096]
//   scratch: T at [8448,12544), tb at [12544,12608)

#define NBATCH 256
#define NSEQ   512
#define DIM    64

typedef __attribute__((ext_vector_type(8))) short short8;
typedef __attribute__((ext_vector_type(4))) float f32x4;

#define MFMA16(a,b,c) __builtin_amdgcn_mfma_f32_16x16x32_bf16(a,b,c,0,0,0)

union BF2 { __hip_bfloat162 b; short2 s; };

__device__ __forceinline__ void cvt2(float f, unsigned short &h, unsigned short &l) {
    unsigned u = __float_as_uint(f);
    unsigned hb = (u + 0x7FFFu + ((u >> 16) & 1u)) >> 16;
    h = (unsigned short)hb;
    float r = f - __uint_as_float(hb << 16);
    unsigned u2 = __float_as_uint(r);
    l = (unsigned short)((u2 + 0x7FFFu + ((u2 >> 16) & 1u)) >> 16);
}

__device__ __forceinline__ void cvt8(const f32x4 a, const f32x4 b, short8 &hi, short8 &lo) {
    BF2 h0, h1, h2, h3;
    h0.b = __float22bfloat162_rn(make_float2(a[0], a[1]));
    h1.b = __float22bfloat162_rn(make_float2(a[2], a[3]));
    h2.b = __float22bfloat162_rn(make_float2(b[0], b[1]));
    h3.b = __float22bfloat162_rn(make_float2(b[2], b[3]));
    hi = short8{h0.s.x, h0.s.y, h1.s.x, h1.s.y, h2.s.x, h2.s.y, h3.s.x, h3.s.y};
    BF2 l0, l1, l2, l3;
    l0.b = __float22bfloat162_rn(make_float2(a[0] - __bfloat162float(h0.b.x),
                                             a[1] - __bfloat162float(h0.b.y)));
    l1.b = __float22bfloat162_rn(make_float2(a[2] - __bfloat162float(h1.b.x),
                                             a[3] - __bfloat162float(h1.b.y)));
    l2.b = __float22bfloat162_rn(make_float2(b[0] - __bfloat162float(h2.b.x),
                                             b[1] - __bfloat162float(h2.b.y)));
    l3.b = __float22bfloat162_rn(make_float2(b[2] - __bfloat162float(h3.b.x),
                                             b[3] - __bfloat162float(h3.b.y)));
    lo = short8{l0.s.x, l0.s.y, l1.s.x, l1.s.y, l2.s.x, l2.s.y, l3.s.x, l3.s.y};
}

// ---- prep1: block d computes T[d,:] = M[d,:]@Wi and tb[d] = M[d,:]·bi ----
__global__ __launch_bounds__(64) void coatt_prep1(
    const float* __restrict__ M, const float* __restrict__ Wi,
    const float* __restrict__ bi, float* __restrict__ ws)
{
    __shared__ float Ml[64];
    const int d = blockIdx.x, f = threadIdx.x;
    Ml[f] = M[d*64 + f];
    __syncthreads();
    float s = 0.f;
    #pragma unroll 8
    for (int e = 0; e < 64; ++e) s = fmaf(Ml[e], Wi[e*64 + f], s);
    ws[8448 + d*64 + f] = s;
    float p = Ml[f] * bi[f];
    #pragma unroll
    for (int off = 1; off < 64; off <<= 1) p += __shfl_xor(p, off, 64);
    if (f == 0) ws[12544 + d] = p;
}

// ---- prep2: block c computes E[c,:] (frag-packed hi/lo), a[c]; block 0 also g, s0 ----
__global__ __launch_bounds__(64) void coatt_prep2(
    const float* __restrict__ Wu, const float* __restrict__ bu,
    float* __restrict__ ws)
{
    __shared__ float col[64];
    const int c = blockIdx.x, f = threadIdx.x;
    const float* T = ws + 8448;
    col[f] = Wu[f*64 + c];          // Wu[d=f][c]
    __syncthreads();
    float s = 0.f;
    #pragma unroll 8
    for (int d = 0; d < 64; ++d) s = fmaf(col[d], T[d*64 + f], s);
    unsigned short* efh = (unsigned short*)(ws + 4352);
    unsigned short* efl = efh + 4096;
    unsigned short h, l;
    cvt2(s, h, l);
    const int ko = c >> 5, quad = (c >> 3) & 3, j = c & 7;
    const int ft = f >> 4, f15 = f & 15;
    const int p = ft*1024 + ko*512 + (quad*16 + f15)*8 + j;
    efh[p] = h; efl[p] = l;
    float pa = col[f] * ws[12544 + f];
    #pragma unroll
    for (int off = 1; off < 64; off <<= 1) pa += __shfl_xor(pa, off, 64);
    if (f == 0) ws[4096 + c] = pa;
    if (c == 0) {
        float sg = 0.f;
        #pragma unroll 8
        for (int d = 0; d < 64; ++d) sg = fmaf(bu[d], T[d*64 + f], sg);
        ws[4160 + f] = sg;
        float ps = bu[f] * ws[12544 + f];
        #pragma unroll
        for (int off = 1; off < 64; off <<= 1) ps += __shfl_xor(ps, off, 64);
        if (f == 0) ws[4224] = ps;
    }
}

// LDS layout (dynamic, bytes):
//  [0,65536)         YH  tau-permuted frag-packed bf16-hi of i_fea[b]
//  [65536,131072)    YL  frag-packed bf16-lo
//  [131072,147456)   colp 8 x 512 f32 (per-wave col maxes, written once)
//  [147456,149504)   uscore 512 f32
//  [149504,149568)   red 16 f32
#define LDS_BYTES 149568

__global__ __launch_bounds__(512, 2) void coatt_main(
    const float* __restrict__ u_fea, const float* __restrict__ i_fea,
    const float* __restrict__ ws, float* __restrict__ out)
{
    extern __shared__ char sm[];
    unsigned short* YH = (unsigned short*)sm;
    unsigned short* YL = (unsigned short*)(sm + 65536);
    float* colp   = (float*)(sm + 131072);
    float* uscore = (float*)(sm + 147456);
    float* red    = (float*)(sm + 149504);

    const int t    = threadIdx.x;
    const int lane = t & 63, w = t >> 6, quad = lane >> 4, l15 = lane & 15;
    const int b = blockIdx.x;
    const float* ub = u_fea + (size_t)b * NSEQ * DIM;
    const float* ib = i_fea + (size_t)b * NSEQ * DIM;

    // ---- E fragments (regs; same packing as rounds 2-4, used as A-operand) ----
    const unsigned short* efh = (const unsigned short*)(ws + 4352);
    const unsigned short* efl = efh + 4096;
    short8 EH[4][2], EL[4][2];
    #pragma unroll
    for (int ft = 0; ft < 4; ++ft)
        #pragma unroll
        for (int ko = 0; ko < 2; ++ko) {
            EH[ft][ko] = *(const short8*)(efh + ((ft*2+ko)*64 + lane)*8);
            EL[ft][ko] = *(const short8*)(efl + ((ft*2+ko)*64 + lane)*8);
        }
    // per-lane bias/az vectors
    f32x4 gq[4];
    #pragma unroll
    for (int ft = 0; ft < 4; ++ft) gq[ft] = *(const f32x4*)(ws + 4160 + ft*16 + quad*4);
    const f32x4 av0 = *(const f32x4*)(ws + 4096 + quad*8);
    const f32x4 av1 = *(const f32x4*)(ws + 4096 + quad*8 + 4);
    const f32x4 av2 = *(const f32x4*)(ws + 4096 + 32 + quad*8);
    const f32x4 av3 = *(const f32x4*)(ws + 4096 + 32 + quad*8 + 4);
    const float s0 = ws[4224];

    // ---- Y-pack: tau-permuted bf16 hi/lo frags, lane-contiguous writes ----
    // wave w packs tiles w*4..w*4+3; task=(tile,p); lane handles m=tile*16+l15,
    // k0 = p*16+quad*4 and k0+32 (this IS tau's slot->k map).
    #pragma unroll
    for (int bt = 0; bt < 2; ++bt) {
        f32x4 ya[4], yb[4];
        #pragma unroll
        for (int q = 0; q < 4; ++q) {
            const int task = bt*4 + q;
            const int tile = w*4 + (task >> 1);
            const int p = task & 1;
            const float* yp = ib + (size_t)(tile*16 + l15)*64 + p*16 + quad*4;
            ya[q] = *(const f32x4*)yp;
            yb[q] = *(const f32x4*)(yp + 32);
        }
        #pragma unroll
        for (int q = 0; q < 4; ++q) {
            const int task = bt*4 + q;
            const int tile = w*4 + (task >> 1);
            const int p = task & 1;
            short8 sh, sl;
            cvt8(ya[q], yb[q], sh, sl);
            const int off = tile*1024 + p*512 + lane*8;
            *(short8*)(YH + off) = sh;
            *(short8*)(YL + off) = sl;
        }
    }

    // ---- X-gen (transpose-free): X^T tiles = MFMA(A=E-frag, B=U-frag) ----
    const int base = w*64;
    f32x4 u[4][4];
    #pragma unroll
    for (int g = 0; g < 4; ++g) {
        const float* up = ub + (size_t)(base + g*16 + l15)*64 + quad*8;
        u[g][0] = *(const f32x4*)up;
        u[g][1] = *(const f32x4*)(up + 4);
        u[g][2] = *(const f32x4*)(up + 32);
        u[g][3] = *(const f32x4*)(up + 36);
    }
    short8 XH[4][2], XL[4][2];
    f32x4 rv[4];
    #pragma unroll
    for (int g = 0; g < 4; ++g) {
        short8 UH0, UL0, UH1, UL1;
        cvt8(u[g][0], u[g][1], UH0, UL0);
        cvt8(u[g][2], u[g][3], UH1, UL1);
        // r[n] partial dot on already-loaded U values
        float rp = 0.f;
        #pragma unroll
        for (int e = 0; e < 4; ++e) rp = fmaf(u[g][0][e], av0[e], rp);
        #pragma unroll
        for (int e = 0; e < 4; ++e) rp = fmaf(u[g][1][e], av1[e], rp);
        #pragma unroll
        for (int e = 0; e < 4; ++e) rp = fmaf(u[g][2][e], av2[e], rp);
        #pragma unroll
        for (int e = 0; e < 4; ++e) rp = fmaf(u[g][3][e], av3[e], rp);
        rp += __shfl_xor(rp, 16, 64);
        rp += __shfl_xor(rp, 32, 64);
        rp += s0;                      // lane l15 holds r[base+g*16+l15]
        f32x4 ct[4];
        #pragma unroll
        for (int ft = 0; ft < 4; ++ft) {
            f32x4 c = gq[ft];          // +g bias folded (f = ft*16+quad*4+rg)
            c = MFMA16(EH[ft][0], UH0, c);
            c = MFMA16(EH[ft][1], UH1, c);
            c = MFMA16(EH[ft][0], UL0, c);
            c = MFMA16(EH[ft][1], UL1, c);
            c = MFMA16(EL[ft][0], UH0, c);
            c = MFMA16(EL[ft][1], UH1, c);
            ct[ft] = c;
        }
        // tau register-rename: A-frag half p = (ct[p], ct[2+p])
        cvt8(ct[0], ct[2], XH[g][0], XL[g][0]);
        cvt8(ct[1], ct[3], XH[g][1], XL[g][1]);
        #pragma unroll
        for (int rg = 0; rg < 4; ++rg)
            rv[g][rg] = __shfl(rp, quad*4 + rg, 64);
    }
    __syncthreads();   // Y visible to all waves

    // ---- S-loop over 32 m-tiles ----
    f32x4 rm[4];
    #pragma unroll
    for (int g = 0; g < 4; ++g)
        rm[g] = (f32x4){-FLT_MAX, -FLT_MAX, -FLT_MAX, -FLT_MAX};
    for (int T = 0; T < 32; ++T) {
        const unsigned short* yh2 = YH + T*1024 + lane*8;
        const unsigned short* yl2 = YL + T*1024 + lane*8;
        const short8 BH0 = *(const short8*)(yh2);
        const short8 BH1 = *(const short8*)(yh2 + 512);
        const short8 BL0 = *(const short8*)(yl2);
        const short8 BL1 = *(const short8*)(yl2 + 512);
        float cg[4];
        #pragma unroll
        for (int g = 0; g < 4; ++g) {
            f32x4 c = rv[g];           // +r[n] folded into C-init
            c = MFMA16(XH[g][0], BH0, c);
            c = MFMA16(XH[g][1], BH1, c);
            c = MFMA16(XH[g][0], BL0, c);
            c = MFMA16(XH[g][1], BL1, c);
            c = MFMA16(XL[g][0], BH0, c);
            c = MFMA16(XL[g][1], BH1, c);
            rm[g][0] = fmaxf(rm[g][0], c[0]);
            rm[g][1] = fmaxf(rm[g][1], c[1]);
            rm[g][2] = fmaxf(rm[g][2], c[2]);
            rm[g][3] = fmaxf(rm[g][3], c[3]);
            cg[g] = fmaxf(fmaxf(c[0], c[1]), fmaxf(c[2], c[3]));
        }
        float cm = fmaxf(fmaxf(cg[0], cg[1]), fmaxf(cg[2], cg[3]));
        cm = fmaxf(cm, __shfl_xor(cm, 16, 64));
        cm = fmaxf(cm, __shfl_xor(cm, 32, 64));
        if (lane < 16) colp[w*512 + T*16 + lane] = cm;   // single store, no RMW
    }
    // ---- row-max write ----
    #pragma unroll
    for (int g = 0; g < 4; ++g)
        #pragma unroll
        for (int rg = 0; rg < 4; ++rg) {
            float v = rm[g][rg];
            v = fmaxf(v, __shfl_xor(v, 1, 64));
            v = fmaxf(v, __shfl_xor(v, 2, 64));
            v = fmaxf(v, __shfl_xor(v, 4, 64));
            v = fmaxf(v, __shfl_xor(v, 8, 64));
            if (l15 == 0) uscore[base + g*16 + quad*4 + rg] = v;
        }
    __syncthreads();

    // ---- softmax(uscore) -> p_u ----
    {
        float v = uscore[t];
        float m = v;
        #pragma unroll
        for (int off = 1; off < 64; off <<= 1) m = fmaxf(m, __shfl_xor(m, off, 64));
        if (lane == 0) red[w] = m;
        __syncthreads();
        m = red[0];
        #pragma unroll
        for (int q = 1; q < 8; ++q) m = fmaxf(m, red[q]);
        const float e = __expf(v - m);
        float s = e;
        #pragma unroll
        for (int off = 1; off < 64; off <<= 1) s += __shfl_xor(s, off, 64);
        if (lane == 0) red[8+w] = s;
        __syncthreads();
        float sum = red[8];
        #pragma unroll
        for (int q = 1; q < 8; ++q) sum += red[8+q];
        out[(size_t)b*NSEQ + t] = e * (1.0f / sum);
    }
    __syncthreads();
    // ---- softmax(col max over 8 wave-slices) -> p_i ----
    {
        float v = colp[t];
        #pragma unroll
        for (int s8 = 1; s8 < 8; ++s8) v = fmaxf(v, colp[s8*512 + t]);
        float m = v;
        #pragma unroll
        for (int off = 1; off < 64; off <<= 1) m = fmaxf(m, __shfl_xor(m, off, 64));
        if (lane == 0) red[w] = m;
        __syncthreads();
        m = red[0];
        #pragma unroll
        for (int q = 1; q < 8; ++q) m = fmaxf(m, red[q]);
        const float e = __expf(v - m);
        float s = e;
        #pragma unroll
        for (int off = 1; off < 64; off <<= 1) s += __shfl_xor(s, off, 64);
        if (lane == 0) red[8+w] = s;
        __syncthreads();
        float sum = red[8];
        #pragma unroll
        for (int q = 1; q < 8; ++q) sum += red[8+q];
        out[(size_t)NBATCH*NSEQ + (size_t)b*NSEQ + t] = e * (1.0f / sum);
    }
}

extern "C" void kernel_launch(void* const* d_in, const int* in_sizes, int n_in,
                              void* d_out, int out_size, void* d_ws, size_t ws_size,
                              hipStream_t stream) {
    const float* u_fea = (const float*)d_in[0];
    const float* i_fea = (const float*)d_in[1];
    const float* M     = (const float*)d_in[2];
    const float* Wu    = (const float*)d_in[3];
    const float* bu    = (const float*)d_in[4];
    const float* Wi    = (const float*)d_in[5];
    const float* bi    = (const float*)d_in[6];
    float* out = (float*)d_out;
    float* ws  = (float*)d_ws;

    coatt_prep1<<<64, 64, 0, stream>>>(M, Wi, bi, ws);
    coatt_prep2<<<64, 64, 0, stream>>>(Wu, bu, ws);
    coatt_main<<<NBATCH, 512, LDS_BYTES, stream>>>(u_fea, i_fea, ws, out);
}